// Round 1
// baseline (2327.515 us; speedup 1.0000x reference)
//
#include <hip/hip_runtime.h>

#define B_ 32
#define P_ 196
#define T_ 32
#define E_ 512
#define H_ 512
#define A_ 256
#define V_ 30000
#define FEAT_ 2048

typedef unsigned short u16;
typedef __attribute__((ext_vector_type(8))) short bf16x8;   // 8 bf16 = 4 VGPR
typedef __attribute__((ext_vector_type(4))) float fx4;

#define MFMA16 __builtin_amdgcn_mfma_f32_16x16x32_bf16

__device__ __forceinline__ u16 f2b(float f){
  unsigned u = __builtin_bit_cast(unsigned, f);
  u += 0x7FFFu + ((u >> 16) & 1u);
  return (u16)(u >> 16);
}
__device__ __forceinline__ float b2f(u16 h){
  unsigned u = ((unsigned)h) << 16;
  return __builtin_bit_cast(float, u);
}
__device__ __forceinline__ float sigm(float x){ return 1.f/(1.f + __expf(-x)); }

// ---------------- f32 -> bf16 convert, 8 elems/thread ----------------
__global__ void k_convert(const float* __restrict__ src, u16* __restrict__ dst, int n8){
  int i = blockIdx.x*256 + threadIdx.x;
  if (i >= n8) return;
  const float4* s = (const float4*)src + (size_t)i*2;
  float4 a = s[0], b = s[1];
  ushort4* d = (ushort4*)dst + (size_t)i*2;
  d[0] = make_ushort4(f2b(a.x), f2b(a.y), f2b(a.z), f2b(a.w));
  d[1] = make_ushort4(f2b(b.x), f2b(b.y), f2b(b.z), f2b(b.w));
}

// ---------------- embedding gather -> bf16, row r = t*32+b ----------------
__global__ void k_gather(const float* __restrict__ emb, const int* __restrict__ cap,
                         u16* __restrict__ dst){
  int r = blockIdx.x;            // 1024 rows
  int l = threadIdx.x;           // 64
  int t = r >> 5, b = r & 31;
  int c = cap[b*T_ + t];
  const float4* s = (const float4*)(emb + (size_t)c*E_) + l*2;
  float4 a = s[0], bb = s[1];
  ushort4* d = (ushort4*)(dst + (size_t)r*E_) + l*2;
  d[0] = make_ushort4(f2b(a.x), f2b(a.y), f2b(a.z), f2b(a.w));
  d[1] = make_ushort4(f2b(bb.x), f2b(bb.y), f2b(bb.z), f2b(bb.w));
}

// ---------------- pack Wd [256][512] into MFMA fragment order ----------------
// frag = ((s*4+q)*4+kw)*4+ks ; elem = frag*512 + l*8 + j
__global__ void k_pack_att2(const float* __restrict__ Wd, u16* __restrict__ dst){
  int eid = blockIdx.x*256 + threadIdx.x;
  if (eid >= 256*512) return;
  int j = eid & 7, l = (eid >> 3) & 63, frag = eid >> 9;
  int ks = frag & 3, kw = (frag >> 2) & 3, q = (frag >> 4) & 3, s = frag >> 6;
  int n = s*64 + q*16 + (l & 15);
  int k = kw*128 + ks*32 + ((l >> 4) << 3) + j;
  dst[eid] = f2b(Wd[n*512 + k]);
}

// ---------------- pack layer-0 gate weights (permuted rows), K=1536 ----------------
// permuted col n' = s*64+q*16+r  <->  orig row = q*512+s*16+r  (gates i,f,g,o)
// frag = ((s*4+q)*4+kw)*12+ks
__global__ void k_pack_g0(const float* __restrict__ Wih, const float* __restrict__ Whh,
                          u16* __restrict__ dst){
  int eid = blockIdx.x*256 + threadIdx.x;
  if (eid >= 6144*512) return;
  int j = eid & 7, l = (eid >> 3) & 63, frag = eid >> 9;
  int ks = frag % 12; int rest = frag / 12;
  int kw = rest & 3, q = (rest >> 2) & 3, s = rest >> 4;
  int n = q*512 + s*16 + (l & 15);
  int k = kw*384 + ks*32 + ((l >> 4) << 3) + j;
  float v = (k < 1024) ? Wih[(size_t)n*1024 + k] : Whh[(size_t)n*512 + (k - 1024)];
  dst[eid] = f2b(v);
}

// ---------------- pack layer-1 gate weights, K=1024 ----------------
// frag = ((s*4+q)*4+kw)*8+ks
__global__ void k_pack_g1(const float* __restrict__ Wih, const float* __restrict__ Whh,
                          u16* __restrict__ dst){
  int eid = blockIdx.x*256 + threadIdx.x;
  if (eid >= 4096*512) return;
  int j = eid & 7, l = (eid >> 3) & 63, frag = eid >> 9;
  int ks = frag & 7, kw = (frag >> 3) & 3, q = (frag >> 5) & 3, s = frag >> 7;
  int n = q*512 + s*16 + (l & 15);
  int k = kw*256 + ks*32 + ((l >> 4) << 3) + j;
  float v = (k < 512) ? Wih[(size_t)n*512 + k] : Whh[(size_t)n*512 + (k - 512)];
  dst[eid] = f2b(v);
}

// ---------------- permuted bias: b_ih + b_hh ----------------
__global__ void k_bias_pack(const float* __restrict__ bih, const float* __restrict__ bhh,
                            float* __restrict__ dst){
  int n = blockIdx.x*256 + threadIdx.x;
  if (n >= 2048) return;
  int c = n & 15, q = (n >> 4) & 3, s = n >> 6;
  int orig = q*512 + s*16 + c;
  dst[n] = bih[orig] + bhh[orig];
}

// ---------------- generic bf16 MFMA GEMM: C = A[M,K] @ W[N,K]^T + bias ----------------
// MODE 0: relu -> bf16 out   1: -> bf16 out   2: -> f32 out   3: clip±10 -> f32, row remap (t,b)->(b,t)
template<int MODE>
__launch_bounds__(256)
__global__ void k_gemm(const u16* __restrict__ A, const u16* __restrict__ W,
                       const float* __restrict__ bias, float* __restrict__ outF,
                       u16* __restrict__ outB, int M, int N, int K){
  __shared__ __align__(16) u16 As[128][40];
  __shared__ __align__(16) u16 Bs[128][40];
  int tid = threadIdx.x;
  int l = tid & 63, w = tid >> 6;
  int wr = w >> 1, wc = w & 1;
  int m0 = blockIdx.y * 128, n0 = blockIdx.x * 128;
  fx4 acc[4][4];
  #pragma unroll
  for (int i=0;i<4;i++)
    #pragma unroll
    for (int j=0;j<4;j++) acc[i][j] = (fx4){0.f,0.f,0.f,0.f};
  int r = tid >> 2, seg = tid & 3;
  int lr = l & 15, lg = l >> 4;
  for (int k0 = 0; k0 < K; k0 += 32){
    *(uint4*)&As[r][seg*8]    = *(const uint4*)(A + (size_t)(m0 + r)*K + k0 + seg*8);
    *(uint4*)&As[r+64][seg*8] = *(const uint4*)(A + (size_t)(m0 + r + 64)*K + k0 + seg*8);
    uint4 z = {0u,0u,0u,0u};
    int rb = n0 + r;
    *(uint4*)&Bs[r][seg*8]    = (rb < N)      ? *(const uint4*)(W + (size_t)rb*K + k0 + seg*8) : z;
    *(uint4*)&Bs[r+64][seg*8] = (rb+64 < N)   ? *(const uint4*)(W + (size_t)(rb+64)*K + k0 + seg*8) : z;
    __syncthreads();
    bf16x8 av[4], bv[4];
    #pragma unroll
    for (int mi=0; mi<4; mi++) av[mi] = *(const bf16x8*)&As[wr*64 + mi*16 + lr][lg*8];
    #pragma unroll
    for (int ni=0; ni<4; ni++) bv[ni] = *(const bf16x8*)&Bs[wc*64 + ni*16 + lr][lg*8];
    #pragma unroll
    for (int mi=0; mi<4; mi++)
      #pragma unroll
      for (int ni=0; ni<4; ni++)
        acc[mi][ni] = MFMA16(av[mi], bv[ni], acc[mi][ni], 0, 0, 0);
    __syncthreads();
  }
  #pragma unroll
  for (int mi=0; mi<4; mi++)
    #pragma unroll
    for (int ni=0; ni<4; ni++){
      int col = n0 + wc*64 + ni*16 + lr;
      if (col >= N) continue;
      float bvs = bias[col];
      #pragma unroll
      for (int reg=0; reg<4; reg++){
        int rowm = m0 + wr*64 + mi*16 + lg*4 + reg;
        float v = acc[mi][ni][reg] + bvs;
        if (MODE == 0){ v = fmaxf(v, 0.f); outB[(size_t)rowm*N + col] = f2b(v); }
        else if (MODE == 1){ outB[(size_t)rowm*N + col] = f2b(v); }
        else if (MODE == 2){ outF[(size_t)rowm*N + col] = v; }
        else {
          v = fminf(fmaxf(v, -10.f), 10.f);
          int bb = rowm & 31, tt = rowm >> 5;
          outF[(size_t)(bb*T_ + tt)*V_ + col] = v;
        }
      }
    }
}

// ---------------- LayerNorm over 512 (bf16 in/out), 1 wave/row ----------------
__global__ void k_ln1(const u16* __restrict__ pre, const float* __restrict__ g,
                      const float* __restrict__ bt, u16* __restrict__ enc){
  int row = blockIdx.x; int l = threadIdx.x;
  bf16x8 vv = *(const bf16x8*)(pre + (size_t)row*E_ + l*8);
  float x[8]; float s = 0.f;
  #pragma unroll
  for (int i=0;i<8;i++){ x[i] = b2f((u16)vv[i]); s += x[i]; }
  #pragma unroll
  for (int off=32; off; off>>=1) s += __shfl_xor(s, off, 64);
  float mean = s * (1.f/512.f);
  float vs = 0.f;
  #pragma unroll
  for (int i=0;i<8;i++){ float d = x[i]-mean; vs += d*d; }
  #pragma unroll
  for (int off=32; off; off>>=1) vs += __shfl_xor(vs, off, 64);
  float inv = rsqrtf(vs*(1.f/512.f) + 1e-5f);
  int c0 = l*8;
  u16 o[8];
  #pragma unroll
  for (int i=0;i<8;i++) o[i] = f2b((x[i]-mean)*inv*g[c0+i] + bt[c0+i]);
  ushort4* d = (ushort4*)(enc + (size_t)row*E_ + c0);
  d[0] = make_ushort4(o[0],o[1],o[2],o[3]);
  d[1] = make_ushort4(o[4],o[5],o[6],o[7]);
}

// ---------------- LayerNorm over 256 + relu (f32 in, bf16 out) ----------------
__global__ void k_ln2(const float* __restrict__ pre1, const float* __restrict__ g,
                      const float* __restrict__ bb, u16* __restrict__ hid){
  int row = blockIdx.x; int l = threadIdx.x;
  float4 v = *(const float4*)(pre1 + (size_t)row*256 + l*4);
  float x[4] = {v.x, v.y, v.z, v.w};
  float s = x[0]+x[1]+x[2]+x[3];
  #pragma unroll
  for (int off=32; off; off>>=1) s += __shfl_xor(s, off, 64);
  float mean = s * (1.f/256.f);
  float vs = 0.f;
  #pragma unroll
  for (int i=0;i<4;i++){ float d = x[i]-mean; vs += d*d; }
  #pragma unroll
  for (int off=32; off; off>>=1) vs += __shfl_xor(vs, off, 64);
  float inv = rsqrtf(vs*(1.f/256.f) + 1e-5f);
  int c0 = l*4;
  u16 o[4];
  #pragma unroll
  for (int i=0;i<4;i++) o[i] = f2b(fmaxf((x[i]-mean)*inv*g[c0+i] + bb[c0+i], 0.f));
  *(ushort4*)(hid + (size_t)row*256 + c0) = make_ushort4(o[0],o[1],o[2],o[3]);
}

// ---------------- att2 = h1 @ Wd^T + bd  (MFMA, M=32, k-split over 4 waves) ----------------
__launch_bounds__(256)
__global__ void k_att2(const u16* __restrict__ xh1, const u16* __restrict__ Wdpk,
                       const float* __restrict__ bd, float* __restrict__ att2){
  __shared__ float part[4][32][16];
  int tid = threadIdx.x, l = tid & 63, kw = tid >> 6, s = blockIdx.x;
  int lr = l & 15, lg = l >> 4;
  bf16x8 a[2][4];
  #pragma unroll
  for (int mi=0;mi<2;mi++)
    #pragma unroll
    for (int ks=0;ks<4;ks++){
      int b = mi*16 + lr;
      int k = kw*128 + ks*32 + lg*8;
      a[mi][ks] = *(const bf16x8*)(xh1 + b*1024 + 512 + k);
    }
  for (int q=0;q<4;q++){
    fx4 acc[2]; acc[0] = (fx4){0,0,0,0}; acc[1] = (fx4){0,0,0,0};
    const u16* wp = Wdpk + (size_t)((((s*4+q)*4+kw)*4))*512 + l*8;
    #pragma unroll
    for (int ks=0;ks<4;ks++){
      bf16x8 bf8 = *(const bf16x8*)(wp + ks*512);
      acc[0] = MFMA16(a[0][ks], bf8, acc[0], 0,0,0);
      acc[1] = MFMA16(a[1][ks], bf8, acc[1], 0,0,0);
    }
    #pragma unroll
    for (int mi=0;mi<2;mi++)
      #pragma unroll
      for (int reg=0;reg<4;reg++)
        part[kw][mi*16 + lg*4 + reg][lr] = acc[mi][reg];
    __syncthreads();
    #pragma unroll
    for (int pp=0;pp<2;pp++){
      int pid = tid + pp*256;
      int b = pid >> 4, c = pid & 15;
      int n = s*64 + q*16 + c;
      att2[b*256 + n] = part[0][b][c]+part[1][b][c]+part[2][b][c]+part[3][b][c] + bd[n];
    }
    __syncthreads();
  }
}

// ---------------- attention: e, softmax, ctx; writes xh0 [emb|ctx|...] ----------------
__launch_bounds__(256)
__global__ void k_attn(const float* __restrict__ att2, const u16* __restrict__ att1b,
                       const u16* __restrict__ enc16, const float* __restrict__ Wf,
                       const float* __restrict__ bfp, const u16* __restrict__ embs,
                       u16* __restrict__ xh0dst, int t){
  __shared__ float a2[256];
  __shared__ float wfv[256];
  __shared__ float ev[256];
  __shared__ float red[8];
  int b = blockIdx.x, tid = threadIdx.x, l = tid & 63, w = tid >> 6;
  a2[tid]  = att2[b*256 + tid];
  wfv[tid] = Wf[tid];
  __syncthreads();
  for (int pi=0; pi<49; pi++){
    int p = w*49 + pi;
    ushort4 av4 = *(const ushort4*)(att1b + (size_t)(b*P_ + p)*A_ + l*4);
    int j0 = l*4;
    float sum = fmaxf(b2f(av4.x) + a2[j0],   0.f)*wfv[j0]
              + fmaxf(b2f(av4.y) + a2[j0+1], 0.f)*wfv[j0+1]
              + fmaxf(b2f(av4.z) + a2[j0+2], 0.f)*wfv[j0+2]
              + fmaxf(b2f(av4.w) + a2[j0+3], 0.f)*wfv[j0+3];
    #pragma unroll
    for (int off=32; off; off>>=1) sum += __shfl_xor(sum, off, 64);
    if (l == 0) ev[p] = sum + bfp[0];
  }
  __syncthreads();
  float v = (tid < P_) ? ev[tid] : -1e30f;
  float m = v;
  #pragma unroll
  for (int off=32; off; off>>=1) m = fmaxf(m, __shfl_xor(m, off, 64));
  if (l == 0) red[w] = m;
  __syncthreads();
  m = fmaxf(fmaxf(red[0],red[1]), fmaxf(red[2],red[3]));
  float ex = (tid < P_) ? __expf(v - m) : 0.f;
  __syncthreads();
  ev[tid] = ex;
  float ssum = ex;
  #pragma unroll
  for (int off=32; off; off>>=1) ssum += __shfl_xor(ssum, off, 64);
  if (l == 0) red[4+w] = ssum;
  __syncthreads();
  float inv = 1.f/(red[4]+red[5]+red[6]+red[7]);
  u16* dst = xh0dst + b*1536;
  for (int cc=0; cc<2; cc++){
    int c = cc*256 + tid;
    float acc = 0.f;
    const u16* ep = enc16 + (size_t)(b*P_)*E_ + c;
    for (int p=0; p<P_; p++) acc += ev[p] * b2f(ep[(size_t)p*E_]);
    dst[512 + c] = f2b(acc * inv);
  }
  const u16* es = embs + (size_t)(t*32 + b)*E_;
  dst[tid] = es[tid];
  dst[tid + 256] = es[tid + 256];
}

// ---------------- gates GEMM + fused LSTM cell ----------------
// G=0: A=xh0[pt] (stride1536,K=1536); writes h0 -> xh1[pt][b*1024+h] and xh0[1-pt][b*1536+1024+h]
// G=1: A=xh1[pt] (stride1024,K=1024); writes h1 -> xh1[1-pt][b*1024+512+h] and h1all[(t*32+b)*512+h]
template<int G>
__launch_bounds__(256)
__global__ void k_gates(const u16* __restrict__ xhA, const u16* __restrict__ Wpk,
                        const float* __restrict__ biasp, float* __restrict__ cbuf,
                        u16* __restrict__ h_dst0, u16* __restrict__ h_dst1, int t){
  constexpr int NKS = (G == 0) ? 12 : 8;
  constexpr int STRIDE = (G == 0) ? 1536 : 1024;
  __shared__ float part[4][32][16];
  __shared__ float gsum[4][32][16];
  int tid = threadIdx.x, l = tid & 63, kw = tid >> 6, s = blockIdx.x;
  int lr = l & 15, lg = l >> 4;
  bf16x8 a[2][NKS];
  #pragma unroll
  for (int mi=0;mi<2;mi++)
    #pragma unroll
    for (int ks=0;ks<NKS;ks++){
      int bb = mi*16 + lr;
      int k = kw*(NKS*32) + ks*32 + lg*8;
      a[mi][ks] = *(const bf16x8*)(xhA + bb*STRIDE + k);
    }
  for (int q=0;q<4;q++){
    fx4 acc0 = (fx4){0,0,0,0}, acc1 = (fx4){0,0,0,0};
    const u16* wp = Wpk + (size_t)(((s*4+q)*4+kw)*NKS)*512 + l*8;
    #pragma unroll
    for (int ks=0;ks<NKS;ks++){
      bf16x8 bf8 = *(const bf16x8*)(wp + ks*512);
      acc0 = MFMA16(a[0][ks], bf8, acc0, 0,0,0);
      acc1 = MFMA16(a[1][ks], bf8, acc1, 0,0,0);
    }
    #pragma unroll
    for (int reg=0;reg<4;reg++){
      part[kw][lg*4+reg][lr]      = acc0[reg];
      part[kw][16+lg*4+reg][lr]   = acc1[reg];
    }
    __syncthreads();
    #pragma unroll
    for (int pp=0;pp<2;pp++){
      int pid = tid + pp*256;
      int bb = pid >> 4, c = pid & 15;
      gsum[q][bb][c] = part[0][bb][c]+part[1][bb][c]+part[2][bb][c]+part[3][bb][c]
                     + biasp[s*64 + q*16 + c];
    }
    __syncthreads();
  }
  #pragma unroll
  for (int pp=0;pp<2;pp++){
    int pid = tid + pp*256;
    int bb = pid >> 4, c = pid & 15;
    int h = s*16 + c;
    float gi = gsum[0][bb][c], gf = gsum[1][bb][c], gg = gsum[2][bb][c], go = gsum[3][bb][c];
    float* cp = cbuf + bb*512 + h;
    float cold = *cp;
    float cn = sigm(gf)*cold + sigm(gi)*tanhf(gg);
    *cp = cn;
    float hn = sigm(go)*tanhf(cn);
    u16 hb = f2b(hn);
    if (G == 0){
      h_dst0[bb*1024 + h] = hb;
      h_dst1[bb*1536 + 1024 + h] = hb;
    } else {
      h_dst0[bb*1024 + 512 + h] = hb;
      h_dst1[(size_t)(t*32 + bb)*512 + h] = hb;
    }
  }
}

extern "C" void kernel_launch(void* const* d_in, const int* in_sizes, int n_in,
                              void* d_out, int out_size, void* d_ws, size_t ws_size,
                              hipStream_t stream){
  (void)in_sizes; (void)n_in; (void)out_size; (void)ws_size;
  const float* features = (const float*)d_in[0];
  const int*   captions = (const int*)d_in[1];
  const float* Wad  = (const float*)d_in[2];
  const float* bad  = (const float*)d_in[3];
  const float* g_ad = (const float*)d_in[4];
  const float* b_ad = (const float*)d_in[5];
  const float* We   = (const float*)d_in[6];
  const float* be   = (const float*)d_in[7];
  const float* Wd   = (const float*)d_in[8];
  const float* bd   = (const float*)d_in[9];
  const float* Wf   = (const float*)d_in[10];
  const float* bfp  = (const float*)d_in[11];
  const float* emb  = (const float*)d_in[12];
  const float* W_ih0 = (const float*)d_in[13];
  const float* W_hh0 = (const float*)d_in[14];
  const float* b_ih0 = (const float*)d_in[15];
  const float* b_hh0 = (const float*)d_in[16];
  const float* W_ih1 = (const float*)d_in[17];
  const float* W_hh1 = (const float*)d_in[18];
  const float* b_ih1 = (const float*)d_in[19];
  const float* b_hh1 = (const float*)d_in[20];
  const float* W1  = (const float*)d_in[21];
  const float* b1  = (const float*)d_in[22];
  const float* g1  = (const float*)d_in[23];
  const float* bb1 = (const float*)d_in[24];
  const float* W2  = (const float*)d_in[25];
  const float* b2  = (const float*)d_in[26];
  float* out = (float*)d_out;

  char* wsb = (char*)d_ws;
  size_t off = 0;
  auto alloc = [&](size_t bytes)->char*{
    char* p = wsb + off; off += (bytes + 255) & ~(size_t)255; return p;
  };
  u16* fb16    = (u16*)alloc((size_t)6272*2048*2);
  u16* Wad16   = (u16*)alloc((size_t)512*2048*2);
  u16* We16    = (u16*)alloc((size_t)256*512*2);
  u16* W1_16   = (u16*)alloc((size_t)256*512*2);
  u16* W2_16   = (u16*)alloc((size_t)30000*256*2);
  u16* Wdpk    = (u16*)alloc((size_t)256*512*2);
  u16* Wg0pk   = (u16*)alloc((size_t)2048*1536*2);
  u16* Wg1pk   = (u16*)alloc((size_t)2048*1024*2);
  float* bias0p = (float*)alloc(2048*4);
  float* bias1p = (float*)alloc(2048*4);
  u16* embs16  = (u16*)alloc((size_t)1024*512*2);
  u16* pre16   = (u16*)alloc((size_t)6272*512*2);
  u16* enc16   = (u16*)alloc((size_t)6272*512*2);
  u16* att1_16 = (u16*)alloc((size_t)6272*256*2);
  float* att2g = (float*)alloc(32*256*4);
  u16* xh0     = (u16*)alloc((size_t)2*32*1536*2);   // start of zeroed region
  u16* xh1     = (u16*)alloc((size_t)2*32*1024*2);
  float* c0buf = (float*)alloc(32*512*4);
  float* c1buf = (float*)alloc(32*512*4);            // end of zeroed region
  u16* h1all16 = (u16*)alloc((size_t)1024*512*2);
  float* pre1  = (float*)alloc((size_t)1024*256*4);
  u16* hid16   = (u16*)alloc((size_t)1024*256*2);

  auto cdiv = [](int a, int b){ return (a+b-1)/b; };

  // zero recurrent state (xh0, xh1, c0, c1 are contiguous: 196608+131072+65536+65536)
  hipMemsetAsync(xh0, 0, 458752, stream);

  // prep: converts / packs / gather
  k_convert<<<cdiv(6272*2048/8,256),256,0,stream>>>(features, fb16, 6272*2048/8);
  k_convert<<<cdiv(512*2048/8,256),256,0,stream>>>(Wad, Wad16, 512*2048/8);
  k_convert<<<cdiv(256*512/8,256),256,0,stream>>>(We, We16, 256*512/8);
  k_convert<<<cdiv(256*512/8,256),256,0,stream>>>(W1, W1_16, 256*512/8);
  k_convert<<<cdiv(30000*256/8,256),256,0,stream>>>(W2, W2_16, 30000*256/8);
  k_pack_att2<<<cdiv(256*512,256),256,0,stream>>>(Wd, Wdpk);
  k_pack_g0<<<cdiv(6144*512,256),256,0,stream>>>(W_ih0, W_hh0, Wg0pk);
  k_pack_g1<<<cdiv(4096*512,256),256,0,stream>>>(W_ih1, W_hh1, Wg1pk);
  k_bias_pack<<<8,256,0,stream>>>(b_ih0, b_hh0, bias0p);
  k_bias_pack<<<8,256,0,stream>>>(b_ih1, b_hh1, bias1p);
  k_gather<<<1024,64,0,stream>>>(emb, captions, embs16);

  // encoder: adapter GEMM (+relu), LN, att1 GEMM
  k_gemm<0><<<dim3(4,49),256,0,stream>>>(fb16, Wad16, bad, nullptr, pre16, 6272, 512, 2048);
  k_ln1<<<6272,64,0,stream>>>(pre16, g_ad, b_ad, enc16);
  k_gemm<1><<<dim3(2,49),256,0,stream>>>(enc16, We16, be, nullptr, att1_16, 6272, 256, 512);

  // recurrence
  u16* xh0buf[2] = { xh0, xh0 + 32*1536 };
  u16* xh1buf[2] = { xh1, xh1 + 32*1024 };
  for (int t = 0; t < T_; t++){
    int pt = t & 1;
    k_att2<<<4,256,0,stream>>>(xh1buf[pt], Wdpk, bd, att2g);
    k_attn<<<32,256,0,stream>>>(att2g, att1_16, enc16, Wf, bfp, embs16, xh0buf[pt], t);
    k_gates<0><<<32,256,0,stream>>>(xh0buf[pt], Wg0pk, bias0p, c0buf,
                                    xh1buf[pt], xh0buf[1-pt], t);
    k_gates<1><<<32,256,0,stream>>>(xh1buf[pt], Wg1pk, bias1p, c1buf,
                                    xh1buf[1-pt], h1all16, t);
  }

  // batched output head
  k_gemm<2><<<dim3(2,8),256,0,stream>>>(h1all16, W1_16, b1, pre1, nullptr, 1024, 256, 512);
  k_ln2<<<1024,64,0,stream>>>(pre1, g1, bb1, hid16);
  k_gemm<3><<<dim3(235,8),256,0,stream>>>(hid16, W2_16, b2, out, nullptr, 1024, 30000, 256);
}